// Round 8
// baseline (675.039 us; speedup 1.0000x reference)
//
#include <hip/hip_runtime.h>
#include <hip/hip_fp16.h>
#include <math.h>

// ---------------------------------------------------------------------------
// GraphNet: 3x EdgeConv (fully linearized) + GAT(2 heads, concat=False)
//
// out[d] = relu( (Σ_{e→d} h[src_e]) @ W1 + B5[d] @ W2 + deg[d]·c )
//   W1 = wn@wc_top, W2 = we@wc_bot, c = bn@wc_top + be@wc_bot + bc
// Precision policy (R6): h stays FP32 (bf16 h compounded to absmax 12.4);
//   G stored FP16 (single rounding into a convex combination, absmax 0.25).
// CSR build (R7 post-mortem): k_scatter was top kernel — 84 MB HBM writes for
//   6.4 MB payload (line-granular amplification) + 800k atomics. Now:
//   k_prep = histogram + edge-rank (atomicAdd return) + B5 via fp32 atomics
//   (coalesced EA read); k_scatter = atomic-free, single random 4B stream.
// EC layer = fused gather(16-lane groups, 8-deep load ladder)+tiled GEMM
//   (4x4 micro-tile, K-unroll capped at 2 — R3 spill lesson).
// ---------------------------------------------------------------------------

#define TPB 256

typedef unsigned int u32;

__device__ inline float2 f16unpack2(u32 u) {
    __half2 h = *reinterpret_cast<__half2*>(&u);
    return __half22float2(h);
}
__device__ inline u32 f16pack2(float lo, float hi) {
    __half2 h = __floats2half2_rn(lo, hi);
    return *reinterpret_cast<u32*>(&h);
}
__device__ inline void fma_f16x8(float* acc, uint4 v, float w) {
    float2 t;
    t = f16unpack2(v.x); acc[0] = fmaf(w, t.x, acc[0]); acc[1] = fmaf(w, t.y, acc[1]);
    t = f16unpack2(v.y); acc[2] = fmaf(w, t.x, acc[2]); acc[3] = fmaf(w, t.y, acc[3]);
    t = f16unpack2(v.z); acc[4] = fmaf(w, t.x, acc[4]); acc[5] = fmaf(w, t.y, acc[5]);
    t = f16unpack2(v.w); acc[6] = fmaf(w, t.x, acc[6]); acc[7] = fmaf(w, t.y, acc[7]);
}

#define MAC4(acc, a, w0, w1, w2, w3)                                           \
    acc.x = fmaf(a.x, w0.x, acc.x); acc.y = fmaf(a.x, w0.y, acc.y);            \
    acc.z = fmaf(a.x, w0.z, acc.z); acc.w = fmaf(a.x, w0.w, acc.w);            \
    acc.x = fmaf(a.y, w1.x, acc.x); acc.y = fmaf(a.y, w1.y, acc.y);            \
    acc.z = fmaf(a.y, w1.z, acc.z); acc.w = fmaf(a.y, w1.w, acc.w);            \
    acc.x = fmaf(a.z, w2.x, acc.x); acc.y = fmaf(a.z, w2.y, acc.y);            \
    acc.z = fmaf(a.z, w2.z, acc.z); acc.w = fmaf(a.z, w2.w, acc.w);            \
    acc.x = fmaf(a.w, w3.x, acc.x); acc.y = fmaf(a.w, w3.y, acc.y);            \
    acc.z = fmaf(a.w, w3.z, acc.z); acc.w = fmaf(a.w, w3.w, acc.w);

// ---- k_prep: degree histogram + edge rank + B5 atomic accumulation ---------
__global__ __launch_bounds__(TPB) void k_prep(const int* __restrict__ dst, const float* __restrict__ EA,
                                              int* __restrict__ cnt, int* __restrict__ rank,
                                              float* __restrict__ B5, int E) {
    int e = blockIdx.x * TPB + threadIdx.x;
    if (e < E) {
        int d = dst[e];
        rank[e] = atomicAdd(&cnt[d], 1);
        const float* p = EA + (size_t)e * 5;
        float* b = B5 + (size_t)d * 5;
        atomicAdd(b + 0, p[0]);
        atomicAdd(b + 1, p[1]);
        atomicAdd(b + 2, p[2]);
        atomicAdd(b + 3, p[3]);
        atomicAdd(b + 4, p[4]);
    }
}

// ---------------- scan (exclusive, 2-level) ----------------
__global__ __launch_bounds__(TPB) void k_scan1(int* __restrict__ data, int* __restrict__ partials, int n) {
    __shared__ int s[TPB];
    int i = blockIdx.x * TPB + threadIdx.x;
    int v = (i < n) ? data[i] : 0;
    s[threadIdx.x] = v;
    __syncthreads();
    for (int off = 1; off < TPB; off <<= 1) {
        int t = (threadIdx.x >= off) ? s[threadIdx.x - off] : 0;
        __syncthreads();
        s[threadIdx.x] += t;
        __syncthreads();
    }
    if (i < n) data[i] = s[threadIdx.x] - v;  // exclusive
    if (threadIdx.x == TPB - 1) partials[blockIdx.x] = s[TPB - 1];
}

__global__ __launch_bounds__(1024) void k_scan2(int* __restrict__ partials, int nb) {
    __shared__ int s[1024];
    int v = (threadIdx.x < nb) ? partials[threadIdx.x] : 0;
    s[threadIdx.x] = v;
    __syncthreads();
    for (int off = 1; off < 1024; off <<= 1) {
        int t = (threadIdx.x >= off) ? s[threadIdx.x - off] : 0;
        __syncthreads();
        s[threadIdx.x] += t;
        __syncthreads();
    }
    if (threadIdx.x < nb) partials[threadIdx.x] = s[threadIdx.x] - v;  // exclusive
}

__global__ __launch_bounds__(TPB) void k_scan3(int* __restrict__ data, const int* __restrict__ partials,
                                               int n, int total) {
    int i = blockIdx.x * TPB + threadIdx.x;
    if (i < n) data[i] += partials[blockIdx.x];
    if (i == 0) data[n] = total;
}

// ---- atomic-free scatter: idx = row_start[dst] + rank ----------------------
__global__ __launch_bounds__(TPB) void k_scatter(const int* __restrict__ src, const int* __restrict__ dst,
                                                 const int* __restrict__ rank, const int* __restrict__ row_start,
                                                 int* __restrict__ csr_src, int E) {
    int e = blockIdx.x * TPB + threadIdx.x;
    if (e < E) {
        int idx = row_start[dst[e]] + rank[e];
        csr_src[idx] = src[e];
    }
}

// ---------------- weight folding ----------------
__global__ __launch_bounds__(TPB) void k_combine(const float* __restrict__ wn, const float* __restrict__ bn,
                                                 const float* __restrict__ we, const float* __restrict__ be,
                                                 const float* __restrict__ wc, const float* __restrict__ bc,
                                                 float* __restrict__ W1, float* __restrict__ W2,
                                                 float* __restrict__ cv) {
    int tid = threadIdx.x;
    for (int idx = tid; idx < 64 * 64; idx += TPB) {
        int i = idx >> 6, j = idx & 63;
        float acc = 0.f;
        #pragma unroll 8
        for (int k = 0; k < 64; k++) acc = fmaf(wn[i * 64 + k], wc[k * 64 + j], acc);
        W1[idx] = acc;
    }
    for (int idx = tid; idx < 5 * 64; idx += TPB) {
        int i = idx >> 6, j = idx & 63;
        float acc = 0.f;
        #pragma unroll 8
        for (int k = 0; k < 64; k++) acc = fmaf(we[i * 64 + k], wc[(64 + k) * 64 + j], acc);
        W2[idx] = acc;
    }
    for (int j = tid; j < 64; j += TPB) {
        float acc = bc[j];
        for (int k = 0; k < 64; k++) {
            acc = fmaf(bn[k], wc[k * 64 + j], acc);
            acc = fmaf(be[k], wc[(64 + k) * 64 + j], acc);
        }
        cv[j] = acc;
    }
}

// ---- fused EC layer: group-gather into LDS A-tile, then tiled GEMM ---------
__global__ __launch_bounds__(TPB) void k_ec_fused(const float* __restrict__ H,
                                                  const int* __restrict__ row_start,
                                                  const int* __restrict__ csr_src,
                                                  const float* __restrict__ Wfold,  // W1(4096)|W2(320)|cv(64)
                                                  const float* __restrict__ B5,
                                                  float* __restrict__ OUT, int n) {
    __shared__ float Alds[64 * 68];
    __shared__ float Wlds[64 * 68];
    const int t = threadIdx.x;
    const int base = blockIdx.x * 64;

    // stage W
    {
        int r16 = t >> 4, cc = (t & 15) * 4;
        #pragma unroll
        for (int rep = 0; rep < 4; rep++) {
            int r = rep * 16 + r16;
            *(float4*)&Wlds[r * 68 + cc] = *(const float4*)&Wfold[r * 64 + cc];
        }
    }

    // gather phase: 16 lane-groups, 4 rows each, 8-deep load ladder
    const int lane = t & 63;
    const int lid = lane & 15;
    const int gbase = lane & 48;
    const int gid = t >> 4;
    const int c4 = lid * 4;
    for (int i = 0; i < 4; i++) {
        int r = gid * 4 + i;
        int node = base + r;
        float4 acc = make_float4(0.f, 0.f, 0.f, 0.f);
        if (node < n) {
            int beg = row_start[node], end = row_start[node + 1];
            for (int chunk = beg; chunk < end; chunk += 16) {
                int cdeg = min(end - chunk, 16);
                int s_l = (chunk + lid < end) ? csr_src[chunk + lid] : 0;
                int it = 0;
                for (; it + 7 < cdeg; it += 8) {
                    int se0 = __shfl(s_l, gbase + it);
                    int se1 = __shfl(s_l, gbase + it + 1);
                    int se2 = __shfl(s_l, gbase + it + 2);
                    int se3 = __shfl(s_l, gbase + it + 3);
                    int se4 = __shfl(s_l, gbase + it + 4);
                    int se5 = __shfl(s_l, gbase + it + 5);
                    int se6 = __shfl(s_l, gbase + it + 6);
                    int se7 = __shfl(s_l, gbase + it + 7);
                    float4 v0 = *(const float4*)&H[(size_t)se0 * 64 + c4];
                    float4 v1 = *(const float4*)&H[(size_t)se1 * 64 + c4];
                    float4 v2 = *(const float4*)&H[(size_t)se2 * 64 + c4];
                    float4 v3 = *(const float4*)&H[(size_t)se3 * 64 + c4];
                    float4 v4 = *(const float4*)&H[(size_t)se4 * 64 + c4];
                    float4 v5 = *(const float4*)&H[(size_t)se5 * 64 + c4];
                    float4 v6 = *(const float4*)&H[(size_t)se6 * 64 + c4];
                    float4 v7 = *(const float4*)&H[(size_t)se7 * 64 + c4];
                    acc.x += ((v0.x + v1.x) + (v2.x + v3.x)) + ((v4.x + v5.x) + (v6.x + v7.x));
                    acc.y += ((v0.y + v1.y) + (v2.y + v3.y)) + ((v4.y + v5.y) + (v6.y + v7.y));
                    acc.z += ((v0.z + v1.z) + (v2.z + v3.z)) + ((v4.z + v5.z) + (v6.z + v7.z));
                    acc.w += ((v0.w + v1.w) + (v2.w + v3.w)) + ((v4.w + v5.w) + (v6.w + v7.w));
                }
                for (; it + 3 < cdeg; it += 4) {
                    int se0 = __shfl(s_l, gbase + it);
                    int se1 = __shfl(s_l, gbase + it + 1);
                    int se2 = __shfl(s_l, gbase + it + 2);
                    int se3 = __shfl(s_l, gbase + it + 3);
                    float4 v0 = *(const float4*)&H[(size_t)se0 * 64 + c4];
                    float4 v1 = *(const float4*)&H[(size_t)se1 * 64 + c4];
                    float4 v2 = *(const float4*)&H[(size_t)se2 * 64 + c4];
                    float4 v3 = *(const float4*)&H[(size_t)se3 * 64 + c4];
                    acc.x += (v0.x + v1.x) + (v2.x + v3.x);
                    acc.y += (v0.y + v1.y) + (v2.y + v3.y);
                    acc.z += (v0.z + v1.z) + (v2.z + v3.z);
                    acc.w += (v0.w + v1.w) + (v2.w + v3.w);
                }
                for (; it < cdeg; it++) {
                    int se = __shfl(s_l, gbase + it);
                    float4 v = *(const float4*)&H[(size_t)se * 64 + c4];
                    acc.x += v.x; acc.y += v.y; acc.z += v.z; acc.w += v.w;
                }
            }
        }
        *(float4*)&Alds[r * 68 + c4] = acc;
    }
    __syncthreads();

    // GEMM phase
    const int r0 = (t >> 4) * 4, c0 = (t & 15) * 4;
    float4 acc0 = make_float4(0.f, 0.f, 0.f, 0.f), acc1 = acc0, acc2 = acc0, acc3 = acc0;
    #pragma unroll 2
    for (int k = 0; k < 64; k += 4) {
        float4 a0 = *(float4*)&Alds[(r0 + 0) * 68 + k];
        float4 a1 = *(float4*)&Alds[(r0 + 1) * 68 + k];
        float4 a2 = *(float4*)&Alds[(r0 + 2) * 68 + k];
        float4 a3 = *(float4*)&Alds[(r0 + 3) * 68 + k];
        float4 w0 = *(float4*)&Wlds[(k + 0) * 68 + c0];
        float4 w1 = *(float4*)&Wlds[(k + 1) * 68 + c0];
        float4 w2 = *(float4*)&Wlds[(k + 2) * 68 + c0];
        float4 w3 = *(float4*)&Wlds[(k + 3) * 68 + c0];
        MAC4(acc0, a0, w0, w1, w2, w3);
        MAC4(acc1, a1, w0, w1, w2, w3);
        MAC4(acc2, a2, w0, w1, w2, w3);
        MAC4(acc3, a3, w0, w1, w2, w3);
    }
    float4 w2c[5];
    #pragma unroll
    for (int j = 0; j < 5; j++) w2c[j] = *(const float4*)&Wfold[4096 + j * 64 + c0];
    const float4 cv4 = *(const float4*)&Wfold[4416 + c0];
    #define EC_STORE(i, acc)                                                        \
        { int row = base + r0 + i;                                                  \
          if (row < n) {                                                            \
              const float* bp = B5 + (size_t)row * 5;                               \
              float deg = (float)(row_start[row + 1] - row_start[row]);             \
              float4 q;                                                             \
              q.x = deg * cv4.x; q.y = deg * cv4.y;                                 \
              q.z = deg * cv4.z; q.w = deg * cv4.w;                                 \
              for (int j = 0; j < 5; j++) {                                         \
                  float b = bp[j];                                                  \
                  q.x = fmaf(b, w2c[j].x, q.x); q.y = fmaf(b, w2c[j].y, q.y);       \
                  q.z = fmaf(b, w2c[j].z, q.z); q.w = fmaf(b, w2c[j].w, q.w);       \
              }                                                                     \
              float4 r4;                                                            \
              r4.x = fmaxf(acc.x + q.x, 0.f); r4.y = fmaxf(acc.y + q.y, 0.f);       \
              r4.z = fmaxf(acc.z + q.z, 0.f); r4.w = fmaxf(acc.w + q.w, 0.f);       \
              *(float4*)&OUT[(size_t)row * 64 + c0] = r4; } }
    EC_STORE(0, acc0) EC_STORE(1, acc1) EC_STORE(2, acc2) EC_STORE(3, acc3)
    #undef EC_STORE
}

// ------- GAT GEMM (fp32 in, fp16 G out) + attention scores fused ------------
__global__ __launch_bounds__(TPB) void k_gemm_gat(const float* __restrict__ H, const float* __restrict__ W,
                                                  const float* __restrict__ att_src, const float* __restrict__ att_dst,
                                                  u32* __restrict__ Gh, float* __restrict__ asrc,
                                                  float* __restrict__ adst, int n) {
    __shared__ float Alds[64 * 68];
    __shared__ float Wlds[64 * 132];
    const int t = threadIdx.x;
    const int base = blockIdx.x * 64;
    {
        int r16 = t >> 4, cc = (t & 15) * 4;
        #pragma unroll
        for (int rep = 0; rep < 4; rep++) {
            int r = rep * 16 + r16;
            int row = base + r;
            float4 v = make_float4(0.f, 0.f, 0.f, 0.f);
            if (row < n) v = *(const float4*)&H[(size_t)row * 64 + cc];
            *(float4*)&Alds[r * 68 + cc] = v;
        }
        #pragma unroll
        for (int rep = 0; rep < 8; rep++) {
            int idx4 = (rep * 256 + t) * 4;
            int r = idx4 >> 7, c = idx4 & 127;
            *(float4*)&Wlds[r * 132 + c] = *(const float4*)&W[r * 128 + c];
        }
    }
    __syncthreads();

    const int r0 = (t >> 4) * 4, c0 = (t & 15) * 4;
    float4 p00 = make_float4(0.f, 0.f, 0.f, 0.f), p01 = p00, p02 = p00, p03 = p00;
    float4 p10 = p00, p11 = p00, p12 = p00, p13 = p00;
    #pragma unroll 2
    for (int k = 0; k < 64; k += 4) {
        float4 a0 = *(float4*)&Alds[(r0 + 0) * 68 + k];
        float4 a1 = *(float4*)&Alds[(r0 + 1) * 68 + k];
        float4 a2 = *(float4*)&Alds[(r0 + 2) * 68 + k];
        float4 a3 = *(float4*)&Alds[(r0 + 3) * 68 + k];
        float4 u0 = *(float4*)&Wlds[(k + 0) * 132 + c0];
        float4 u1 = *(float4*)&Wlds[(k + 1) * 132 + c0];
        float4 u2 = *(float4*)&Wlds[(k + 2) * 132 + c0];
        float4 u3 = *(float4*)&Wlds[(k + 3) * 132 + c0];
        MAC4(p00, a0, u0, u1, u2, u3);
        MAC4(p01, a1, u0, u1, u2, u3);
        MAC4(p02, a2, u0, u1, u2, u3);
        MAC4(p03, a3, u0, u1, u2, u3);
        float4 v0 = *(float4*)&Wlds[(k + 0) * 132 + 64 + c0];
        float4 v1 = *(float4*)&Wlds[(k + 1) * 132 + 64 + c0];
        float4 v2 = *(float4*)&Wlds[(k + 2) * 132 + 64 + c0];
        float4 v3 = *(float4*)&Wlds[(k + 3) * 132 + 64 + c0];
        MAC4(p10, a0, v0, v1, v2, v3);
        MAC4(p11, a1, v0, v1, v2, v3);
        MAC4(p12, a2, v0, v1, v2, v3);
        MAC4(p13, a3, v0, v1, v2, v3);
    }
    const float4 as0 = *(const float4*)&att_src[c0];
    const float4 as1 = *(const float4*)&att_src[64 + c0];
    const float4 ad0 = *(const float4*)&att_dst[c0];
    const float4 ad1 = *(const float4*)&att_dst[64 + c0];
    #define DOT4(a, b) (a.x * b.x + a.y * b.y + a.z * b.z + a.w * b.w)
    #define GAT_ROW(i, h0, h1)                                                      \
        { int row = base + r0 + i;                                                  \
          float s0 = DOT4(h0, as0), s1 = DOT4(h1, as1);                             \
          float d0 = DOT4(h0, ad0), d1 = DOT4(h1, ad1);                             \
          s0 += __shfl_xor(s0, 1); s1 += __shfl_xor(s1, 1);                         \
          d0 += __shfl_xor(d0, 1); d1 += __shfl_xor(d1, 1);                         \
          s0 += __shfl_xor(s0, 2); s1 += __shfl_xor(s1, 2);                         \
          d0 += __shfl_xor(d0, 2); d1 += __shfl_xor(d1, 2);                         \
          s0 += __shfl_xor(s0, 4); s1 += __shfl_xor(s1, 4);                         \
          d0 += __shfl_xor(d0, 4); d1 += __shfl_xor(d1, 4);                         \
          s0 += __shfl_xor(s0, 8); s1 += __shfl_xor(s1, 8);                         \
          d0 += __shfl_xor(d0, 8); d1 += __shfl_xor(d1, 8);                         \
          if (row < n) {                                                            \
              uint2 g0; g0.x = f16pack2(h0.x, h0.y); g0.y = f16pack2(h0.z, h0.w);   \
              uint2 g1; g1.x = f16pack2(h1.x, h1.y); g1.y = f16pack2(h1.z, h1.w);   \
              *(uint2*)&Gh[(size_t)row * 64 + (c0 >> 1)] = g0;                      \
              *(uint2*)&Gh[(size_t)row * 64 + 32 + (c0 >> 1)] = g1;                 \
              if ((t & 15) == 0) {                                                  \
                  float2 sv; sv.x = s0; sv.y = s1;                                  \
                  float2 dv; dv.x = d0; dv.y = d1;                                  \
                  *(float2*)&asrc[(size_t)row * 2] = sv;                            \
                  *(float2*)&adst[(size_t)row * 2] = dv; } } }
    GAT_ROW(0, p00, p10) GAT_ROW(1, p01, p11) GAT_ROW(2, p02, p12) GAT_ROW(3, p03, p13)
    #undef GAT_ROW
    #undef DOT4
}

// ----- GAT aggregation: fp16 G; one node per 16-lane group; head=lid>>3 -----
__global__ __launch_bounds__(TPB) void k_gat_agg(const u32* __restrict__ Gh, const int* __restrict__ row_start,
                                                 const int* __restrict__ csr_src, const float* __restrict__ asrc,
                                                 const float* __restrict__ adst, const float* __restrict__ bgat,
                                                 float* __restrict__ OUT, int n) {
    const int node = blockIdx.x * 16 + (threadIdx.x >> 4);
    if (node >= n) return;
    const int lane = threadIdx.x & 63;
    const int lid = lane & 15;
    const int gbase = lane & 48;
    const int head = lid >> 3;
    const int u4 = lid * 4;
    const int beg = row_start[node], end = row_start[node + 1];
    const float2 adv = *(const float2*)&adst[(size_t)node * 2];
    float m0 = -INFINITY, m1 = -INFINITY, d0 = 0.f, d1 = 0.f;
    float A[8] = {0.f, 0.f, 0.f, 0.f, 0.f, 0.f, 0.f, 0.f};
    for (int chunk = beg; chunk < end; chunk += 16) {
        int cdeg = min(end - chunk, 16);
        bool valid = (lid < cdeg);
        int s_l = valid ? csr_src[chunk + lid] : 0;
        float al0 = -INFINITY, al1 = -INFINITY;
        if (valid) {
            float2 av = *(const float2*)&asrc[(size_t)s_l * 2];
            float t0 = av.x + adv.x, t1 = av.y + adv.y;
            al0 = (t0 > 0.f) ? t0 : 0.2f * t0;
            al1 = (t1 > 0.f) ? t1 : 0.2f * t1;
        }
        float cm0 = al0, cm1 = al1;
        #pragma unroll
        for (int off = 1; off < 16; off <<= 1) {
            cm0 = fmaxf(cm0, __shfl_xor(cm0, off));
            cm1 = fmaxf(cm1, __shfl_xor(cm1, off));
        }
        float nm0 = fmaxf(m0, cm0), nm1 = fmaxf(m1, cm1);
        float sc0 = __expf(m0 - nm0), sc1 = __expf(m1 - nm1);  // 0 on first chunk
        float w0 = valid ? __expf(al0 - nm0) : 0.f;
        float w1 = valid ? __expf(al1 - nm1) : 0.f;
        float cd0 = w0, cd1 = w1;
        #pragma unroll
        for (int off = 1; off < 16; off <<= 1) {
            cd0 += __shfl_xor(cd0, off);
            cd1 += __shfl_xor(cd1, off);
        }
        d0 = d0 * sc0 + cd0;
        d1 = d1 * sc1 + cd1;
        float scsel = head ? sc1 : sc0;
        #pragma unroll
        for (int j = 0; j < 8; j++) A[j] *= scsel;
        m0 = nm0; m1 = nm1;
        int it = 0;
        for (; it + 3 < cdeg; it += 4) {
            int sa = __shfl(s_l, gbase + it);
            int sb = __shfl(s_l, gbase + it + 1);
            int sc = __shfl(s_l, gbase + it + 2);
            int sd = __shfl(s_l, gbase + it + 3);
            float w0a = __shfl(w0, gbase + it),     w1a = __shfl(w1, gbase + it);
            float w0b = __shfl(w0, gbase + it + 1), w1b = __shfl(w1, gbase + it + 1);
            float w0c = __shfl(w0, gbase + it + 2), w1c = __shfl(w1, gbase + it + 2);
            float w0d = __shfl(w0, gbase + it + 3), w1d = __shfl(w1, gbase + it + 3);
            float wa = head ? w1a : w0a;
            float wb = head ? w1b : w0b;
            float wc = head ? w1c : w0c;
            float wd = head ? w1d : w0d;
            uint4 va = *(const uint4*)&Gh[(size_t)sa * 64 + u4];
            uint4 vb = *(const uint4*)&Gh[(size_t)sb * 64 + u4];
            uint4 vc = *(const uint4*)&Gh[(size_t)sc * 64 + u4];
            uint4 vd = *(const uint4*)&Gh[(size_t)sd * 64 + u4];
            fma_f16x8(A, va, wa);
            fma_f16x8(A, vb, wb);
            fma_f16x8(A, vc, wc);
            fma_f16x8(A, vd, wd);
        }
        for (; it + 1 < cdeg; it += 2) {
            int sa = __shfl(s_l, gbase + it);
            int sb = __shfl(s_l, gbase + it + 1);
            float w0a = __shfl(w0, gbase + it),     w1a = __shfl(w1, gbase + it);
            float w0b = __shfl(w0, gbase + it + 1), w1b = __shfl(w1, gbase + it + 1);
            float wa = head ? w1a : w0a;
            float wb = head ? w1b : w0b;
            uint4 va = *(const uint4*)&Gh[(size_t)sa * 64 + u4];
            uint4 vb = *(const uint4*)&Gh[(size_t)sb * 64 + u4];
            fma_f16x8(A, va, wa);
            fma_f16x8(A, vb, wb);
        }
        if (it < cdeg) {
            int sa = __shfl(s_l, gbase + it);
            float w0a = __shfl(w0, gbase + it), w1a = __shfl(w1, gbase + it);
            float wa = head ? w1a : w0a;
            uint4 va = *(const uint4*)&Gh[(size_t)sa * 64 + u4];
            fma_f16x8(A, va, wa);
        }
    }
    float rh = 0.5f / ((head ? d1 : d0) + 1e-16f);
    #pragma unroll
    for (int j = 0; j < 8; j++) {
        A[j] *= rh;
        A[j] += __shfl_xor(A[j], 8);   // combine the two heads
    }
    if (head == 0) {
        int cb = (lid & 7) * 8;
        const float4 bg0 = *(const float4*)&bgat[cb];
        const float4 bg1 = *(const float4*)&bgat[cb + 4];
        float4 o0; o0.x = A[0] + bg0.x; o0.y = A[1] + bg0.y; o0.z = A[2] + bg0.z; o0.w = A[3] + bg0.w;
        float4 o1; o1.x = A[4] + bg1.x; o1.y = A[5] + bg1.y; o1.z = A[6] + bg1.z; o1.w = A[7] + bg1.w;
        float* op = &OUT[(size_t)node * 64 + cb];
        *(float4*)op = o0;
        *(float4*)(op + 4) = o1;
    }
}

extern "C" void kernel_launch(void* const* d_in, const int* in_sizes, int n_in,
                              void* d_out, int out_size, void* d_ws, size_t ws_size,
                              hipStream_t stream) {
    const float* x   = (const float*)d_in[0];
    const int*   ei  = (const int*)d_in[1];
    const float* ea  = (const float*)d_in[2];
    const int N = in_sizes[0] / 64;
    const int E = in_sizes[1] / 2;
    const int* src = ei;
    const int* dst = ei + E;

    const float* wn[3] = {(const float*)d_in[3],  (const float*)d_in[9],  (const float*)d_in[15]};
    const float* bn[3] = {(const float*)d_in[4],  (const float*)d_in[10], (const float*)d_in[16]};
    const float* we[3] = {(const float*)d_in[5],  (const float*)d_in[11], (const float*)d_in[17]};
    const float* be[3] = {(const float*)d_in[6],  (const float*)d_in[12], (const float*)d_in[18]};
    const float* wc[3] = {(const float*)d_in[7],  (const float*)d_in[13], (const float*)d_in[19]};
    const float* bc[3] = {(const float*)d_in[8],  (const float*)d_in[14], (const float*)d_in[20]};
    const float* wgat    = (const float*)d_in[21];
    const float* att_src = (const float*)d_in[22];
    const float* att_dst = (const float*)d_in[23];
    const float* bgat    = (const float*)d_in[24];

    // workspace carve-up (256B aligned)
    char* ws = (char*)d_ws;
    size_t off = 0;
    auto alloc = [&](size_t bytes) -> void* {
        void* p = ws + off;
        off = (off + bytes + 255) & ~(size_t)255;
        return p;
    };
    int*   row_start = (int*)alloc((size_t)(N + 1) * 4);
    int*   partials  = (int*)alloc(1024 * 4);
    int*   rank      = (int*)alloc((size_t)E * 4);
    int*   csr_src   = (int*)alloc((size_t)E * 4);
    float* Wc        = (float*)alloc((size_t)3 * 4480 * 4);   // per layer: W1|W2|cv
    float* B5        = (float*)alloc((size_t)N * 5 * 4);
    float* bufH0     = (float*)alloc((size_t)N * 64 * 4);     // h ping (fp32)
    float* bufH1     = (float*)alloc((size_t)N * 64 * 4);     // h pong (fp32)
    u32*   Gh        = (u32*)alloc((size_t)N * 64 * 4);       // fp16 G [N][128]
    float* asrc      = (float*)alloc((size_t)N * 2 * 4);
    float* adst      = (float*)alloc((size_t)N * 2 * 4);
    float* out = (float*)d_out;

    const int nbN = (N + TPB - 1) / TPB;
    const int nbE = (E + TPB - 1) / TPB;
    const int grpBlocks = (N + 15) / 16;
    const int tiles = (N + 63) / 64;

    // ---- fold weights ----
    for (int l = 0; l < 3; l++) {
        float* W1 = Wc + l * 4480;
        k_combine<<<1, TPB, 0, stream>>>(wn[l], bn[l], we[l], be[l], wc[l], bc[l],
                                         W1, W1 + 4096, W1 + 4416);
    }

    // ---- CSR build: prep (hist + rank + B5 atomics), scan, atomic-free scatter
    hipMemsetAsync(row_start, 0, (size_t)N * 4, stream);
    hipMemsetAsync(B5, 0, (size_t)N * 5 * 4, stream);
    k_prep<<<nbE, TPB, 0, stream>>>(dst, ea, row_start, rank, B5, E);
    k_scan1<<<nbN, TPB, 0, stream>>>(row_start, partials, N);
    k_scan2<<<1, 1024, 0, stream>>>(partials, nbN);
    k_scan3<<<nbN, TPB, 0, stream>>>(row_start, partials, N, E);
    k_scatter<<<nbE, TPB, 0, stream>>>(src, dst, rank, row_start, csr_src, E);

    // ---- 3 fused edge-conv layers ----
    k_ec_fused<<<tiles, TPB, 0, stream>>>(x,     row_start, csr_src, Wc,            B5, bufH0, N);
    k_ec_fused<<<tiles, TPB, 0, stream>>>(bufH0, row_start, csr_src, Wc + 4480,     B5, bufH1, N);
    k_ec_fused<<<tiles, TPB, 0, stream>>>(bufH1, row_start, csr_src, Wc + 2 * 4480, B5, bufH0, N);

    // ---- GAT ----
    k_gemm_gat<<<tiles, TPB, 0, stream>>>(bufH0, wgat, att_src, att_dst, Gh, asrc, adst, N);
    k_gat_agg<<<grpBlocks, TPB, 0, stream>>>(Gh, row_start, csr_src, asrc, adst, bgat, out, N);
}

// Round 9
// 487.395 us; speedup vs baseline: 1.3850x; 1.3850x over previous
//
#include <hip/hip_runtime.h>
#include <hip/hip_fp16.h>
#include <math.h>

// ---------------------------------------------------------------------------
// GraphNet: 3x EdgeConv (fully linearized) + GAT(2 heads, concat=False)
//
// out[d] = relu( (Σ_{e→d} h[src_e]) @ W1 + B5[d] @ W2 + deg[d]·c )
//   W1 = wn@wc_top, W2 = we@wc_bot, c = bn@wc_top + be@wc_bot + bc
// Precision policy (R6): h stays FP32 (bf16 h compounded to absmax 12.4);
//   G stored FP16 (single rounding into a convex combination, absmax 0.25).
// CSR build (R8 post-mortem): random scattered ATOMICS are poison — R8's
//   per-edge 5x fp32 atomicAdd B5 build hit 153 MB writes / 234 us. Now:
//   k_hist (degree + rank via atomicAdd return, coalesced) -> scan ->
//   k_scatter (atomic-free, ONE combined int2{src,e} random 8B stream) ->
//   k_aggB5 (CSR-order gather of L3-resident EA, no atomics).
// EC layer = fused gather(16-lane groups, 8-deep load ladder)+tiled GEMM
//   (4x4 micro-tile, K-unroll capped at 2 — R3 spill lesson).
// ---------------------------------------------------------------------------

#define TPB 256

typedef unsigned int u32;

__device__ inline float2 f16unpack2(u32 u) {
    __half2 h = *reinterpret_cast<__half2*>(&u);
    return __half22float2(h);
}
__device__ inline u32 f16pack2(float lo, float hi) {
    __half2 h = __floats2half2_rn(lo, hi);
    return *reinterpret_cast<u32*>(&h);
}
__device__ inline void fma_f16x8(float* acc, uint4 v, float w) {
    float2 t;
    t = f16unpack2(v.x); acc[0] = fmaf(w, t.x, acc[0]); acc[1] = fmaf(w, t.y, acc[1]);
    t = f16unpack2(v.y); acc[2] = fmaf(w, t.x, acc[2]); acc[3] = fmaf(w, t.y, acc[3]);
    t = f16unpack2(v.z); acc[4] = fmaf(w, t.x, acc[4]); acc[5] = fmaf(w, t.y, acc[5]);
    t = f16unpack2(v.w); acc[6] = fmaf(w, t.x, acc[6]); acc[7] = fmaf(w, t.y, acc[7]);
}

#define MAC4(acc, a, w0, w1, w2, w3)                                           \
    acc.x = fmaf(a.x, w0.x, acc.x); acc.y = fmaf(a.x, w0.y, acc.y);            \
    acc.z = fmaf(a.x, w0.z, acc.z); acc.w = fmaf(a.x, w0.w, acc.w);            \
    acc.x = fmaf(a.y, w1.x, acc.x); acc.y = fmaf(a.y, w1.y, acc.y);            \
    acc.z = fmaf(a.y, w1.z, acc.z); acc.w = fmaf(a.y, w1.w, acc.w);            \
    acc.x = fmaf(a.z, w2.x, acc.x); acc.y = fmaf(a.z, w2.y, acc.y);            \
    acc.z = fmaf(a.z, w2.z, acc.z); acc.w = fmaf(a.z, w2.w, acc.w);            \
    acc.x = fmaf(a.w, w3.x, acc.x); acc.y = fmaf(a.w, w3.y, acc.y);            \
    acc.z = fmaf(a.w, w3.z, acc.z); acc.w = fmaf(a.w, w3.w, acc.w);

// ---- k_hist: degree histogram + edge rank (atomicAdd return) ---------------
__global__ __launch_bounds__(TPB) void k_hist(const int* __restrict__ dst, int* __restrict__ cnt,
                                              int* __restrict__ rank, int E) {
    int e = blockIdx.x * TPB + threadIdx.x;
    if (e < E) rank[e] = atomicAdd(&cnt[dst[e]], 1);
}

// ---------------- scan (exclusive, 2-level) ----------------
__global__ __launch_bounds__(TPB) void k_scan1(int* __restrict__ data, int* __restrict__ partials, int n) {
    __shared__ int s[TPB];
    int i = blockIdx.x * TPB + threadIdx.x;
    int v = (i < n) ? data[i] : 0;
    s[threadIdx.x] = v;
    __syncthreads();
    for (int off = 1; off < TPB; off <<= 1) {
        int t = (threadIdx.x >= off) ? s[threadIdx.x - off] : 0;
        __syncthreads();
        s[threadIdx.x] += t;
        __syncthreads();
    }
    if (i < n) data[i] = s[threadIdx.x] - v;  // exclusive
    if (threadIdx.x == TPB - 1) partials[blockIdx.x] = s[TPB - 1];
}

__global__ __launch_bounds__(1024) void k_scan2(int* __restrict__ partials, int nb) {
    __shared__ int s[1024];
    int v = (threadIdx.x < nb) ? partials[threadIdx.x] : 0;
    s[threadIdx.x] = v;
    __syncthreads();
    for (int off = 1; off < 1024; off <<= 1) {
        int t = (threadIdx.x >= off) ? s[threadIdx.x - off] : 0;
        __syncthreads();
        s[threadIdx.x] += t;
        __syncthreads();
    }
    if (threadIdx.x < nb) partials[threadIdx.x] = s[threadIdx.x] - v;  // exclusive
}

__global__ __launch_bounds__(TPB) void k_scan3(int* __restrict__ data, const int* __restrict__ partials,
                                               int n, int total) {
    int i = blockIdx.x * TPB + threadIdx.x;
    if (i < n) data[i] += partials[blockIdx.x];
    if (i == 0) data[n] = total;
}

// ---- atomic-free scatter: one combined int2{src,e} random 8B stream --------
__global__ __launch_bounds__(TPB) void k_scatter(const int* __restrict__ src, const int* __restrict__ dst,
                                                 const int* __restrict__ rank, const int* __restrict__ row_start,
                                                 int2* __restrict__ csr_se, int E) {
    int e = blockIdx.x * TPB + threadIdx.x;
    if (e < E) {
        int idx = row_start[dst[e]] + rank[e];
        csr_se[idx] = make_int2(src[e], e);
    }
}

// ---- B5[d] = Σ ea over incoming edges (CSR gather, 16-lane group/node) -----
__global__ __launch_bounds__(TPB) void k_aggB5(const int2* __restrict__ csr_se, const int* __restrict__ row_start,
                                               const float* __restrict__ EA, float* __restrict__ B5, int n) {
    const int node = blockIdx.x * 16 + (threadIdx.x >> 4);
    if (node >= n) return;
    const int lid = threadIdx.x & 15;
    const int beg = row_start[node], end = row_start[node + 1];
    float b0 = 0.f, b1 = 0.f, b2 = 0.f, b3 = 0.f, b4 = 0.f;
    for (int j = beg + lid; j < end; j += 16) {
        int e = csr_se[j].y;
        const float* p = EA + (size_t)e * 5;
        b0 += p[0]; b1 += p[1]; b2 += p[2]; b3 += p[3]; b4 += p[4];
    }
    #pragma unroll
    for (int off = 1; off < 16; off <<= 1) {
        b0 += __shfl_xor(b0, off); b1 += __shfl_xor(b1, off);
        b2 += __shfl_xor(b2, off); b3 += __shfl_xor(b3, off);
        b4 += __shfl_xor(b4, off);
    }
    if (lid == 0) {
        float* bp = B5 + (size_t)node * 5;
        bp[0] = b0; bp[1] = b1; bp[2] = b2; bp[3] = b3; bp[4] = b4;
    }
}

// ---------------- weight folding ----------------
__global__ __launch_bounds__(TPB) void k_combine(const float* __restrict__ wn, const float* __restrict__ bn,
                                                 const float* __restrict__ we, const float* __restrict__ be,
                                                 const float* __restrict__ wc, const float* __restrict__ bc,
                                                 float* __restrict__ W1, float* __restrict__ W2,
                                                 float* __restrict__ cv) {
    int tid = threadIdx.x;
    for (int idx = tid; idx < 64 * 64; idx += TPB) {
        int i = idx >> 6, j = idx & 63;
        float acc = 0.f;
        #pragma unroll 8
        for (int k = 0; k < 64; k++) acc = fmaf(wn[i * 64 + k], wc[k * 64 + j], acc);
        W1[idx] = acc;
    }
    for (int idx = tid; idx < 5 * 64; idx += TPB) {
        int i = idx >> 6, j = idx & 63;
        float acc = 0.f;
        #pragma unroll 8
        for (int k = 0; k < 64; k++) acc = fmaf(we[i * 64 + k], wc[(64 + k) * 64 + j], acc);
        W2[idx] = acc;
    }
    for (int j = tid; j < 64; j += TPB) {
        float acc = bc[j];
        for (int k = 0; k < 64; k++) {
            acc = fmaf(bn[k], wc[k * 64 + j], acc);
            acc = fmaf(be[k], wc[(64 + k) * 64 + j], acc);
        }
        cv[j] = acc;
    }
}

// ---- fused EC layer: group-gather into LDS A-tile, then tiled GEMM ---------
__global__ __launch_bounds__(TPB) void k_ec_fused(const float* __restrict__ H,
                                                  const int* __restrict__ row_start,
                                                  const int2* __restrict__ csr_se,
                                                  const float* __restrict__ Wfold,  // W1(4096)|W2(320)|cv(64)
                                                  const float* __restrict__ B5,
                                                  float* __restrict__ OUT, int n) {
    __shared__ float Alds[64 * 68];
    __shared__ float Wlds[64 * 68];
    const int t = threadIdx.x;
    const int base = blockIdx.x * 64;

    // stage W
    {
        int r16 = t >> 4, cc = (t & 15) * 4;
        #pragma unroll
        for (int rep = 0; rep < 4; rep++) {
            int r = rep * 16 + r16;
            *(float4*)&Wlds[r * 68 + cc] = *(const float4*)&Wfold[r * 64 + cc];
        }
    }

    // gather phase: 16 lane-groups, 4 rows each, 8-deep load ladder
    const int lane = t & 63;
    const int lid = lane & 15;
    const int gbase = lane & 48;
    const int gid = t >> 4;
    const int c4 = lid * 4;
    for (int i = 0; i < 4; i++) {
        int r = gid * 4 + i;
        int node = base + r;
        float4 acc = make_float4(0.f, 0.f, 0.f, 0.f);
        if (node < n) {
            int beg = row_start[node], end = row_start[node + 1];
            for (int chunk = beg; chunk < end; chunk += 16) {
                int cdeg = min(end - chunk, 16);
                int s_l = (chunk + lid < end) ? csr_se[chunk + lid].x : 0;
                int it = 0;
                for (; it + 7 < cdeg; it += 8) {
                    int se0 = __shfl(s_l, gbase + it);
                    int se1 = __shfl(s_l, gbase + it + 1);
                    int se2 = __shfl(s_l, gbase + it + 2);
                    int se3 = __shfl(s_l, gbase + it + 3);
                    int se4 = __shfl(s_l, gbase + it + 4);
                    int se5 = __shfl(s_l, gbase + it + 5);
                    int se6 = __shfl(s_l, gbase + it + 6);
                    int se7 = __shfl(s_l, gbase + it + 7);
                    float4 v0 = *(const float4*)&H[(size_t)se0 * 64 + c4];
                    float4 v1 = *(const float4*)&H[(size_t)se1 * 64 + c4];
                    float4 v2 = *(const float4*)&H[(size_t)se2 * 64 + c4];
                    float4 v3 = *(const float4*)&H[(size_t)se3 * 64 + c4];
                    float4 v4 = *(const float4*)&H[(size_t)se4 * 64 + c4];
                    float4 v5 = *(const float4*)&H[(size_t)se5 * 64 + c4];
                    float4 v6 = *(const float4*)&H[(size_t)se6 * 64 + c4];
                    float4 v7 = *(const float4*)&H[(size_t)se7 * 64 + c4];
                    acc.x += ((v0.x + v1.x) + (v2.x + v3.x)) + ((v4.x + v5.x) + (v6.x + v7.x));
                    acc.y += ((v0.y + v1.y) + (v2.y + v3.y)) + ((v4.y + v5.y) + (v6.y + v7.y));
                    acc.z += ((v0.z + v1.z) + (v2.z + v3.z)) + ((v4.z + v5.z) + (v6.z + v7.z));
                    acc.w += ((v0.w + v1.w) + (v2.w + v3.w)) + ((v4.w + v5.w) + (v6.w + v7.w));
                }
                for (; it + 3 < cdeg; it += 4) {
                    int se0 = __shfl(s_l, gbase + it);
                    int se1 = __shfl(s_l, gbase + it + 1);
                    int se2 = __shfl(s_l, gbase + it + 2);
                    int se3 = __shfl(s_l, gbase + it + 3);
                    float4 v0 = *(const float4*)&H[(size_t)se0 * 64 + c4];
                    float4 v1 = *(const float4*)&H[(size_t)se1 * 64 + c4];
                    float4 v2 = *(const float4*)&H[(size_t)se2 * 64 + c4];
                    float4 v3 = *(const float4*)&H[(size_t)se3 * 64 + c4];
                    acc.x += (v0.x + v1.x) + (v2.x + v3.x);
                    acc.y += (v0.y + v1.y) + (v2.y + v3.y);
                    acc.z += (v0.z + v1.z) + (v2.z + v3.z);
                    acc.w += (v0.w + v1.w) + (v2.w + v3.w);
                }
                for (; it < cdeg; it++) {
                    int se = __shfl(s_l, gbase + it);
                    float4 v = *(const float4*)&H[(size_t)se * 64 + c4];
                    acc.x += v.x; acc.y += v.y; acc.z += v.z; acc.w += v.w;
                }
            }
        }
        *(float4*)&Alds[r * 68 + c4] = acc;
    }
    __syncthreads();

    // GEMM phase
    const int r0 = (t >> 4) * 4, c0 = (t & 15) * 4;
    float4 acc0 = make_float4(0.f, 0.f, 0.f, 0.f), acc1 = acc0, acc2 = acc0, acc3 = acc0;
    #pragma unroll 2
    for (int k = 0; k < 64; k += 4) {
        float4 a0 = *(float4*)&Alds[(r0 + 0) * 68 + k];
        float4 a1 = *(float4*)&Alds[(r0 + 1) * 68 + k];
        float4 a2 = *(float4*)&Alds[(r0 + 2) * 68 + k];
        float4 a3 = *(float4*)&Alds[(r0 + 3) * 68 + k];
        float4 w0 = *(float4*)&Wlds[(k + 0) * 68 + c0];
        float4 w1 = *(float4*)&Wlds[(k + 1) * 68 + c0];
        float4 w2 = *(float4*)&Wlds[(k + 2) * 68 + c0];
        float4 w3 = *(float4*)&Wlds[(k + 3) * 68 + c0];
        MAC4(acc0, a0, w0, w1, w2, w3);
        MAC4(acc1, a1, w0, w1, w2, w3);
        MAC4(acc2, a2, w0, w1, w2, w3);
        MAC4(acc3, a3, w0, w1, w2, w3);
    }
    float4 w2c[5];
    #pragma unroll
    for (int j = 0; j < 5; j++) w2c[j] = *(const float4*)&Wfold[4096 + j * 64 + c0];
    const float4 cv4 = *(const float4*)&Wfold[4416 + c0];
    #define EC_STORE(i, acc)                                                        \
        { int row = base + r0 + i;                                                  \
          if (row < n) {                                                            \
              const float* bp = B5 + (size_t)row * 5;                               \
              float deg = (float)(row_start[row + 1] - row_start[row]);             \
              float4 q;                                                             \
              q.x = deg * cv4.x; q.y = deg * cv4.y;                                 \
              q.z = deg * cv4.z; q.w = deg * cv4.w;                                 \
              for (int j = 0; j < 5; j++) {                                         \
                  float b = bp[j];                                                  \
                  q.x = fmaf(b, w2c[j].x, q.x); q.y = fmaf(b, w2c[j].y, q.y);       \
                  q.z = fmaf(b, w2c[j].z, q.z); q.w = fmaf(b, w2c[j].w, q.w);       \
              }                                                                     \
              float4 r4;                                                            \
              r4.x = fmaxf(acc.x + q.x, 0.f); r4.y = fmaxf(acc.y + q.y, 0.f);       \
              r4.z = fmaxf(acc.z + q.z, 0.f); r4.w = fmaxf(acc.w + q.w, 0.f);       \
              *(float4*)&OUT[(size_t)row * 64 + c0] = r4; } }
    EC_STORE(0, acc0) EC_STORE(1, acc1) EC_STORE(2, acc2) EC_STORE(3, acc3)
    #undef EC_STORE
}

// ------- GAT GEMM (fp32 in, fp16 G out) + attention scores fused ------------
__global__ __launch_bounds__(TPB) void k_gemm_gat(const float* __restrict__ H, const float* __restrict__ W,
                                                  const float* __restrict__ att_src, const float* __restrict__ att_dst,
                                                  u32* __restrict__ Gh, float* __restrict__ asrc,
                                                  float* __restrict__ adst, int n) {
    __shared__ float Alds[64 * 68];
    __shared__ float Wlds[64 * 132];
    const int t = threadIdx.x;
    const int base = blockIdx.x * 64;
    {
        int r16 = t >> 4, cc = (t & 15) * 4;
        #pragma unroll
        for (int rep = 0; rep < 4; rep++) {
            int r = rep * 16 + r16;
            int row = base + r;
            float4 v = make_float4(0.f, 0.f, 0.f, 0.f);
            if (row < n) v = *(const float4*)&H[(size_t)row * 64 + cc];
            *(float4*)&Alds[r * 68 + cc] = v;
        }
        #pragma unroll
        for (int rep = 0; rep < 8; rep++) {
            int idx4 = (rep * 256 + t) * 4;
            int r = idx4 >> 7, c = idx4 & 127;
            *(float4*)&Wlds[r * 132 + c] = *(const float4*)&W[r * 128 + c];
        }
    }
    __syncthreads();

    const int r0 = (t >> 4) * 4, c0 = (t & 15) * 4;
    float4 p00 = make_float4(0.f, 0.f, 0.f, 0.f), p01 = p00, p02 = p00, p03 = p00;
    float4 p10 = p00, p11 = p00, p12 = p00, p13 = p00;
    #pragma unroll 2
    for (int k = 0; k < 64; k += 4) {
        float4 a0 = *(float4*)&Alds[(r0 + 0) * 68 + k];
        float4 a1 = *(float4*)&Alds[(r0 + 1) * 68 + k];
        float4 a2 = *(float4*)&Alds[(r0 + 2) * 68 + k];
        float4 a3 = *(float4*)&Alds[(r0 + 3) * 68 + k];
        float4 u0 = *(float4*)&Wlds[(k + 0) * 132 + c0];
        float4 u1 = *(float4*)&Wlds[(k + 1) * 132 + c0];
        float4 u2 = *(float4*)&Wlds[(k + 2) * 132 + c0];
        float4 u3 = *(float4*)&Wlds[(k + 3) * 132 + c0];
        MAC4(p00, a0, u0, u1, u2, u3);
        MAC4(p01, a1, u0, u1, u2, u3);
        MAC4(p02, a2, u0, u1, u2, u3);
        MAC4(p03, a3, u0, u1, u2, u3);
        float4 v0 = *(float4*)&Wlds[(k + 0) * 132 + 64 + c0];
        float4 v1 = *(float4*)&Wlds[(k + 1) * 132 + 64 + c0];
        float4 v2 = *(float4*)&Wlds[(k + 2) * 132 + 64 + c0];
        float4 v3 = *(float4*)&Wlds[(k + 3) * 132 + 64 + c0];
        MAC4(p10, a0, v0, v1, v2, v3);
        MAC4(p11, a1, v0, v1, v2, v3);
        MAC4(p12, a2, v0, v1, v2, v3);
        MAC4(p13, a3, v0, v1, v2, v3);
    }
    const float4 as0 = *(const float4*)&att_src[c0];
    const float4 as1 = *(const float4*)&att_src[64 + c0];
    const float4 ad0 = *(const float4*)&att_dst[c0];
    const float4 ad1 = *(const float4*)&att_dst[64 + c0];
    #define DOT4(a, b) (a.x * b.x + a.y * b.y + a.z * b.z + a.w * b.w)
    #define GAT_ROW(i, h0, h1)                                                      \
        { int row = base + r0 + i;                                                  \
          float s0 = DOT4(h0, as0), s1 = DOT4(h1, as1);                             \
          float d0 = DOT4(h0, ad0), d1 = DOT4(h1, ad1);                             \
          s0 += __shfl_xor(s0, 1); s1 += __shfl_xor(s1, 1);                         \
          d0 += __shfl_xor(d0, 1); d1 += __shfl_xor(d1, 1);                         \
          s0 += __shfl_xor(s0, 2); s1 += __shfl_xor(s1, 2);                         \
          d0 += __shfl_xor(d0, 2); d1 += __shfl_xor(d1, 2);                         \
          s0 += __shfl_xor(s0, 4); s1 += __shfl_xor(s1, 4);                         \
          d0 += __shfl_xor(d0, 4); d1 += __shfl_xor(d1, 4);                         \
          s0 += __shfl_xor(s0, 8); s1 += __shfl_xor(s1, 8);                         \
          d0 += __shfl_xor(d0, 8); d1 += __shfl_xor(d1, 8);                         \
          if (row < n) {                                                            \
              uint2 g0; g0.x = f16pack2(h0.x, h0.y); g0.y = f16pack2(h0.z, h0.w);   \
              uint2 g1; g1.x = f16pack2(h1.x, h1.y); g1.y = f16pack2(h1.z, h1.w);   \
              *(uint2*)&Gh[(size_t)row * 64 + (c0 >> 1)] = g0;                      \
              *(uint2*)&Gh[(size_t)row * 64 + 32 + (c0 >> 1)] = g1;                 \
              if ((t & 15) == 0) {                                                  \
                  float2 sv; sv.x = s0; sv.y = s1;                                  \
                  float2 dv; dv.x = d0; dv.y = d1;                                  \
                  *(float2*)&asrc[(size_t)row * 2] = sv;                            \
                  *(float2*)&adst[(size_t)row * 2] = dv; } } }
    GAT_ROW(0, p00, p10) GAT_ROW(1, p01, p11) GAT_ROW(2, p02, p12) GAT_ROW(3, p03, p13)
    #undef GAT_ROW
    #undef DOT4
}

// ----- GAT aggregation: fp16 G; one node per 16-lane group; head=lid>>3 -----
__global__ __launch_bounds__(TPB) void k_gat_agg(const u32* __restrict__ Gh, const int* __restrict__ row_start,
                                                 const int2* __restrict__ csr_se, const float* __restrict__ asrc,
                                                 const float* __restrict__ adst, const float* __restrict__ bgat,
                                                 float* __restrict__ OUT, int n) {
    const int node = blockIdx.x * 16 + (threadIdx.x >> 4);
    if (node >= n) return;
    const int lane = threadIdx.x & 63;
    const int lid = lane & 15;
    const int gbase = lane & 48;
    const int head = lid >> 3;
    const int u4 = lid * 4;
    const int beg = row_start[node], end = row_start[node + 1];
    const float2 adv = *(const float2*)&adst[(size_t)node * 2];
    float m0 = -INFINITY, m1 = -INFINITY, d0 = 0.f, d1 = 0.f;
    float A[8] = {0.f, 0.f, 0.f, 0.f, 0.f, 0.f, 0.f, 0.f};
    for (int chunk = beg; chunk < end; chunk += 16) {
        int cdeg = min(end - chunk, 16);
        bool valid = (lid < cdeg);
        int s_l = valid ? csr_se[chunk + lid].x : 0;
        float al0 = -INFINITY, al1 = -INFINITY;
        if (valid) {
            float2 av = *(const float2*)&asrc[(size_t)s_l * 2];
            float t0 = av.x + adv.x, t1 = av.y + adv.y;
            al0 = (t0 > 0.f) ? t0 : 0.2f * t0;
            al1 = (t1 > 0.f) ? t1 : 0.2f * t1;
        }
        float cm0 = al0, cm1 = al1;
        #pragma unroll
        for (int off = 1; off < 16; off <<= 1) {
            cm0 = fmaxf(cm0, __shfl_xor(cm0, off));
            cm1 = fmaxf(cm1, __shfl_xor(cm1, off));
        }
        float nm0 = fmaxf(m0, cm0), nm1 = fmaxf(m1, cm1);
        float sc0 = __expf(m0 - nm0), sc1 = __expf(m1 - nm1);  // 0 on first chunk
        float w0 = valid ? __expf(al0 - nm0) : 0.f;
        float w1 = valid ? __expf(al1 - nm1) : 0.f;
        float cd0 = w0, cd1 = w1;
        #pragma unroll
        for (int off = 1; off < 16; off <<= 1) {
            cd0 += __shfl_xor(cd0, off);
            cd1 += __shfl_xor(cd1, off);
        }
        d0 = d0 * sc0 + cd0;
        d1 = d1 * sc1 + cd1;
        float scsel = head ? sc1 : sc0;
        #pragma unroll
        for (int j = 0; j < 8; j++) A[j] *= scsel;
        m0 = nm0; m1 = nm1;
        int it = 0;
        for (; it + 3 < cdeg; it += 4) {
            int sa = __shfl(s_l, gbase + it);
            int sb = __shfl(s_l, gbase + it + 1);
            int sc = __shfl(s_l, gbase + it + 2);
            int sd = __shfl(s_l, gbase + it + 3);
            float w0a = __shfl(w0, gbase + it),     w1a = __shfl(w1, gbase + it);
            float w0b = __shfl(w0, gbase + it + 1), w1b = __shfl(w1, gbase + it + 1);
            float w0c = __shfl(w0, gbase + it + 2), w1c = __shfl(w1, gbase + it + 2);
            float w0d = __shfl(w0, gbase + it + 3), w1d = __shfl(w1, gbase + it + 3);
            float wa = head ? w1a : w0a;
            float wb = head ? w1b : w0b;
            float wc = head ? w1c : w0c;
            float wd = head ? w1d : w0d;
            uint4 va = *(const uint4*)&Gh[(size_t)sa * 64 + u4];
            uint4 vb = *(const uint4*)&Gh[(size_t)sb * 64 + u4];
            uint4 vc = *(const uint4*)&Gh[(size_t)sc * 64 + u4];
            uint4 vd = *(const uint4*)&Gh[(size_t)sd * 64 + u4];
            fma_f16x8(A, va, wa);
            fma_f16x8(A, vb, wb);
            fma_f16x8(A, vc, wc);
            fma_f16x8(A, vd, wd);
        }
        for (; it + 1 < cdeg; it += 2) {
            int sa = __shfl(s_l, gbase + it);
            int sb = __shfl(s_l, gbase + it + 1);
            float w0a = __shfl(w0, gbase + it),     w1a = __shfl(w1, gbase + it);
            float w0b = __shfl(w0, gbase + it + 1), w1b = __shfl(w1, gbase + it + 1);
            float wa = head ? w1a : w0a;
            float wb = head ? w1b : w0b;
            uint4 va = *(const uint4*)&Gh[(size_t)sa * 64 + u4];
            uint4 vb = *(const uint4*)&Gh[(size_t)sb * 64 + u4];
            fma_f16x8(A, va, wa);
            fma_f16x8(A, vb, wb);
        }
        if (it < cdeg) {
            int sa = __shfl(s_l, gbase + it);
            float w0a = __shfl(w0, gbase + it), w1a = __shfl(w1, gbase + it);
            float wa = head ? w1a : w0a;
            uint4 va = *(const uint4*)&Gh[(size_t)sa * 64 + u4];
            fma_f16x8(A, va, wa);
        }
    }
    float rh = 0.5f / ((head ? d1 : d0) + 1e-16f);
    #pragma unroll
    for (int j = 0; j < 8; j++) {
        A[j] *= rh;
        A[j] += __shfl_xor(A[j], 8);   // combine the two heads
    }
    if (head == 0) {
        int cb = (lid & 7) * 8;
        const float4 bg0 = *(const float4*)&bgat[cb];
        const float4 bg1 = *(const float4*)&bgat[cb + 4];
        float4 o0; o0.x = A[0] + bg0.x; o0.y = A[1] + bg0.y; o0.z = A[2] + bg0.z; o0.w = A[3] + bg0.w;
        float4 o1; o1.x = A[4] + bg1.x; o1.y = A[5] + bg1.y; o1.z = A[6] + bg1.z; o1.w = A[7] + bg1.w;
        float* op = &OUT[(size_t)node * 64 + cb];
        *(float4*)op = o0;
        *(float4*)(op + 4) = o1;
    }
}

extern "C" void kernel_launch(void* const* d_in, const int* in_sizes, int n_in,
                              void* d_out, int out_size, void* d_ws, size_t ws_size,
                              hipStream_t stream) {
    const float* x   = (const float*)d_in[0];
    const int*   ei  = (const int*)d_in[1];
    const float* ea  = (const float*)d_in[2];
    const int N = in_sizes[0] / 64;
    const int E = in_sizes[1] / 2;
    const int* src = ei;
    const int* dst = ei + E;

    const float* wn[3] = {(const float*)d_in[3],  (const float*)d_in[9],  (const float*)d_in[15]};
    const float* bn[3] = {(const float*)d_in[4],  (const float*)d_in[10], (const float*)d_in[16]};
    const float* we[3] = {(const float*)d_in[5],  (const float*)d_in[11], (const float*)d_in[17]};
    const float* be[3] = {(const float*)d_in[6],  (const float*)d_in[12], (const float*)d_in[18]};
    const float* wc[3] = {(const float*)d_in[7],  (const float*)d_in[13], (const float*)d_in[19]};
    const float* bc[3] = {(const float*)d_in[8],  (const float*)d_in[14], (const float*)d_in[20]};
    const float* wgat    = (const float*)d_in[21];
    const float* att_src = (const float*)d_in[22];
    const float* att_dst = (const float*)d_in[23];
    const float* bgat    = (const float*)d_in[24];

    // workspace carve-up (256B aligned)
    char* ws = (char*)d_ws;
    size_t off = 0;
    auto alloc = [&](size_t bytes) -> void* {
        void* p = ws + off;
        off = (off + bytes + 255) & ~(size_t)255;
        return p;
    };
    int*   row_start = (int*)alloc((size_t)(N + 1) * 4);
    int*   partials  = (int*)alloc(1024 * 4);
    int*   rank      = (int*)alloc((size_t)E * 4);
    int2*  csr_se    = (int2*)alloc((size_t)E * 8);
    float* Wc        = (float*)alloc((size_t)3 * 4480 * 4);   // per layer: W1|W2|cv
    float* B5        = (float*)alloc((size_t)N * 5 * 4);
    float* bufH0     = (float*)alloc((size_t)N * 64 * 4);     // h ping (fp32)
    float* bufH1     = (float*)alloc((size_t)N * 64 * 4);     // h pong (fp32)
    u32*   Gh        = (u32*)alloc((size_t)N * 64 * 4);       // fp16 G [N][128]
    float* asrc      = (float*)alloc((size_t)N * 2 * 4);
    float* adst      = (float*)alloc((size_t)N * 2 * 4);
    float* out = (float*)d_out;

    const int nbN = (N + TPB - 1) / TPB;
    const int nbE = (E + TPB - 1) / TPB;
    const int grpBlocks = (N + 15) / 16;
    const int tiles = (N + 63) / 64;

    // ---- fold weights ----
    for (int l = 0; l < 3; l++) {
        float* W1 = Wc + l * 4480;
        k_combine<<<1, TPB, 0, stream>>>(wn[l], bn[l], we[l], be[l], wc[l], bc[l],
                                         W1, W1 + 4096, W1 + 4416);
    }

    // ---- CSR build: hist(+rank), scan, atomic-free int2 scatter, B5 gather --
    hipMemsetAsync(row_start, 0, (size_t)N * 4, stream);
    k_hist<<<nbE, TPB, 0, stream>>>(dst, row_start, rank, E);
    k_scan1<<<nbN, TPB, 0, stream>>>(row_start, partials, N);
    k_scan2<<<1, 1024, 0, stream>>>(partials, nbN);
    k_scan3<<<nbN, TPB, 0, stream>>>(row_start, partials, N, E);
    k_scatter<<<nbE, TPB, 0, stream>>>(src, dst, rank, row_start, csr_se, E);
    k_aggB5<<<grpBlocks, TPB, 0, stream>>>(csr_se, row_start, ea, B5, N);

    // ---- 3 fused edge-conv layers ----
    k_ec_fused<<<tiles, TPB, 0, stream>>>(x,     row_start, csr_se, Wc,            B5, bufH0, N);
    k_ec_fused<<<tiles, TPB, 0, stream>>>(bufH0, row_start, csr_se, Wc + 4480,     B5, bufH1, N);
    k_ec_fused<<<tiles, TPB, 0, stream>>>(bufH1, row_start, csr_se, Wc + 2 * 4480, B5, bufH0, N);

    // ---- GAT ----
    k_gemm_gat<<<tiles, TPB, 0, stream>>>(bufH0, wgat, att_src, att_dst, Gh, asrc, adst, N);
    k_gat_agg<<<grpBlocks, TPB, 0, stream>>>(Gh, row_start, csr_se, asrc, adst, bgat, out, N);
}